// Round 1
// baseline (2946.780 us; speedup 1.0000x reference)
//
#include <hip/hip_runtime.h>
#include <hip/hip_bf16.h>
#include <math.h>

// Problem constants
constexpr int kB   = 64;
constexpr int kT   = 77;
constexpr int kD   = 256;
constexpr int kH   = 8;
constexpr int kDH  = 32;
constexpr int kDFF = 2048;
constexpr int kM1  = 400;
constexpr int kMKV = 800;
constexpr float kEPS = 1e-5f;
constexpr float kNEG = -1000000000.0f;

// ---------------------------------------------------------------------------
// Generic batched GEMM: C[b] = A[b] @ W[sid[b]]^T + bias[sid[b]]  (opt. ReLU)
// A: (M,K) row-major, W: (N,K) row-major, C: (M,N) row-major.
// Tiles: BM=32, BN=64, BK=32. 256 threads, each computes 2 rows x 4 cols.
// LDS tiles stored k-major (As[kk][r], Ws[kk][n]) so the inner loop reads
// float2 (b64) + float4 (b128) with conflict-free banking.
// ---------------------------------------------------------------------------
constexpr int BM = 32, BN = 64, BK = 32;

__global__ __launch_bounds__(256) void gemm_kernel(
    const float* __restrict__ A, long long sA, int lda,
    const float* __restrict__ W, long long sW, int ldw,
    const float* __restrict__ bias, long long sB,
    float* __restrict__ C, long long sC, int ldc,
    const int* __restrict__ sid, int M, int N, int K, int relu)
{
    int b = blockIdx.z;
    int s = sid[b];
    const float* Ab = A + (long long)b * sA;
    const float* Wb = W + (long long)s * sW;
    const float* Bb = bias + (long long)s * sB;
    float* Cb = C + (long long)b * sC;
    int tm0 = blockIdx.y * BM, tn0 = blockIdx.x * BN;

    __shared__ float As[BK][BM + 2];   // stride 34: b64-aligned, conflict-free
    __shared__ float Ws[BK][BN + 4];   // stride 68: b128-aligned

    int t = threadIdx.x;
    int tn = t & 15, tm = t >> 4;      // tn 0..15 (col group), tm 0..15 (row group)
    int c0 = tn * 4, r0 = tm * 2;

    float acc[2][4] = {};

    for (int k0 = 0; k0 < K; k0 += BK) {
        // Load A tile (32x32), 4 elts/thread, coalesced along k
        #pragma unroll
        for (int i = 0; i < 4; i++) {
            int id = t + 256 * i;
            int r = id >> 5, kk = id & 31;
            int ar = tm0 + r;
            As[kk][r] = (ar < M) ? Ab[(long long)ar * lda + (k0 + kk)] : 0.f;
        }
        // Load W tile (64x32), 8 elts/thread, coalesced along k
        #pragma unroll
        for (int i = 0; i < 8; i++) {
            int id = t + 256 * i;
            int n = id >> 5, kk = id & 31;
            int wr = tn0 + n;
            Ws[kk][n] = (wr < N) ? Wb[(long long)wr * ldw + (k0 + kk)] : 0.f;
        }
        __syncthreads();
        #pragma unroll
        for (int kk = 0; kk < BK; kk++) {
            float2 av = *(const float2*)&As[kk][r0];
            float4 wv = *(const float4*)&Ws[kk][c0];
            acc[0][0] += av.x * wv.x; acc[0][1] += av.x * wv.y;
            acc[0][2] += av.x * wv.z; acc[0][3] += av.x * wv.w;
            acc[1][0] += av.y * wv.x; acc[1][1] += av.y * wv.y;
            acc[1][2] += av.y * wv.z; acc[1][3] += av.y * wv.w;
        }
        __syncthreads();
    }

    int cg = tn0 + c0;              // N is always a multiple of 64 here
    float4 bv = *(const float4*)&Bb[cg];
    #pragma unroll
    for (int i = 0; i < 2; i++) {
        int r = tm0 + r0 + i;
        if (r < M) {
            float o0 = acc[i][0] + bv.x, o1 = acc[i][1] + bv.y;
            float o2 = acc[i][2] + bv.z, o3 = acc[i][3] + bv.w;
            if (relu) { o0 = fmaxf(o0, 0.f); o1 = fmaxf(o1, 0.f);
                        o2 = fmaxf(o2, 0.f); o3 = fmaxf(o3, 0.f); }
            *(float4*)&Cb[(long long)r * ldc + cg] = make_float4(o0, o1, o2, o3);
        }
    }
}

// ---------------------------------------------------------------------------
// Fused attention: one wave (64 lanes) per (b, h, q-row).
// Scores buffered in LDS (<= 800), exact softmax (max-subtracted), then P@V.
// Key-padding mask: key j uses m1[j] if j < split else m2[j-split].
// ---------------------------------------------------------------------------
__global__ __launch_bounds__(64) void attn_kernel(
    const float* __restrict__ Q, long long sQ, int ldq,
    const float* __restrict__ Kp, long long sK, int ldk,
    const float* __restrict__ Vp, long long sV, int ldv,
    const unsigned char* __restrict__ m1, int sM1,
    const unsigned char* __restrict__ m2, int sM2,
    int split, int nk,
    float* __restrict__ O, long long sO, int ldo, float scale)
{
    int qi = blockIdx.x, h = blockIdx.y, b = blockIdx.z;
    int lane = threadIdx.x;

    __shared__ float qrow[kDH];
    __shared__ float sc[832];

    const float* Qb = Q + (long long)b * sQ + (long long)qi * ldq + h * kDH;
    const float* Kb = Kp + (long long)b * sK + h * kDH;
    const float* Vb = Vp + (long long)b * sV + h * kDH;

    if (lane < kDH) qrow[lane] = Qb[lane];
    __syncthreads();

    // Pass 1: scores + running max
    float m = -INFINITY;
    for (int j0 = 0; j0 < nk; j0 += 64) {
        int j = j0 + lane;
        float sv = -INFINITY;
        if (j < nk) {
            const float* kr = Kb + (long long)j * ldk;
            float dot = 0.f;
            #pragma unroll
            for (int d = 0; d < kDH; d++) dot += qrow[d] * kr[d];
            sv = dot * scale;
            unsigned char msk = (j < split) ? m1[b * sM1 + j] : m2[b * sM2 + (j - split)];
            if (msk) sv = kNEG;
        }
        sc[j0 + lane] = sv;
        m = fmaxf(m, sv);
    }
    #pragma unroll
    for (int off = 32; off >= 1; off >>= 1) m = fmaxf(m, __shfl_xor(m, off));

    // Pass 2: exp + sum
    float sum = 0.f;
    for (int j0 = 0; j0 < nk; j0 += 64) {
        int j = j0 + lane;
        if (j < nk) {
            float p = __expf(sc[j] - m);
            sc[j] = p;
            sum += p;
        }
    }
    #pragma unroll
    for (int off = 32; off >= 1; off >>= 1) sum += __shfl_xor(sum, off);
    float inv = 1.f / sum;
    __syncthreads();

    // Pass 3: O[d] = sum_j p[j] * V[j][d]; lanes split {d = lane&31, half = lane>>5}
    int d = lane & 31, half = lane >> 5;
    float acc = 0.f;
    for (int j = half; j < nk; j += 2)
        acc += sc[j] * Vb[(long long)j * ldv + d];
    acc += __shfl_xor(acc, 32);
    if (lane < kDH)
        O[(long long)b * sO + (long long)qi * ldo + h * kDH + d] = acc * inv;
}

// ---------------------------------------------------------------------------
// Fused residual-add + LayerNorm over D=256. Block = 256 threads = one row.
// ---------------------------------------------------------------------------
__global__ __launch_bounds__(256) void addln_kernel(
    const float* __restrict__ A, const float* __restrict__ R,
    const float* __restrict__ w, const float* __restrict__ bb,
    const int* __restrict__ sid, float* __restrict__ O)
{
    int t = blockIdx.x, b = blockIdx.y, d = threadIdx.x;
    long long base = ((long long)(b * kT + t)) * kD;
    float x = A[base + d] + R[base + d];

    __shared__ float r1[4], r2[4];
    int wid = d >> 6;

    float sacc = x;
    #pragma unroll
    for (int off = 32; off >= 1; off >>= 1) sacc += __shfl_xor(sacc, off);
    if ((d & 63) == 0) r1[wid] = sacc;
    __syncthreads();
    float mean = (r1[0] + r1[1] + r1[2] + r1[3]) * (1.0f / 256.0f);

    float diff = x - mean;
    float s2 = diff * diff;
    #pragma unroll
    for (int off = 32; off >= 1; off >>= 1) s2 += __shfl_xor(s2, off);
    if ((d & 63) == 0) r2[wid] = s2;
    __syncthreads();
    float var = (r2[0] + r2[1] + r2[2] + r2[3]) * (1.0f / 256.0f);

    int s = sid[b];
    float y = diff * rsqrtf(var + kEPS) * w[s * kD + d] + bb[s * kD + d];
    O[base + d] = y;
}

// ---------------------------------------------------------------------------
// Launch
// ---------------------------------------------------------------------------
extern "C" void kernel_launch(void* const* d_in, const int* in_sizes, int n_in,
                              void* d_out, int out_size, void* d_ws, size_t ws_size,
                              hipStream_t stream)
{
    const float*         text   = (const float*)d_in[0];
    const unsigned char* tmask  = (const unsigned char*)d_in[1];
    const float*         im1    = (const float*)d_in[2];
    const unsigned char* immk1  = (const unsigned char*)d_in[3];
    const float*         im2    = (const float*)d_in[4];
    const unsigned char* immk2  = (const unsigned char*)d_in[5];
    const int*           sid    = (const int*)d_in[6];
    const float* sa_in_w  = (const float*)d_in[7];
    const float* sa_in_b  = (const float*)d_in[8];
    const float* sa_out_w = (const float*)d_in[9];
    const float* sa_out_b = (const float*)d_in[10];
    const float* ca_in_w  = (const float*)d_in[11];
    const float* ca_in_b  = (const float*)d_in[12];
    const float* ca_out_w = (const float*)d_in[13];
    const float* ca_out_b = (const float*)d_in[14];
    const float* lin1_w   = (const float*)d_in[15];
    const float* lin1_b   = (const float*)d_in[16];
    const float* lin2_w   = (const float*)d_in[17];
    const float* lin2_b   = (const float*)d_in[18];
    const float* ln1_w    = (const float*)d_in[19];
    const float* ln1_b    = (const float*)d_in[20];
    const float* ln2_w    = (const float*)d_in[21];
    const float* ln2_b    = (const float*)d_in[22];
    const float* ln3_w    = (const float*)d_in[23];
    const float* ln3_b    = (const float*)d_in[24];
    float* out = (float*)d_out;

    // Workspace layout (floats)
    float* ws = (float*)d_ws;
    float* qkv_sa  = ws;                                   // B*T*768
    float* q_ca    = qkv_sa  + (long long)kB * kT * 768;   // B*T*256
    float* kv_ca   = q_ca    + (long long)kB * kT * kD;    // B*800*512
    float* attnbuf = kv_ca   + (long long)kB * kMKV * 512; // B*T*256
    float* tmp     = attnbuf + (long long)kB * kT * kD;    // B*T*256
    float* x1      = tmp     + (long long)kB * kT * kD;    // B*T*256
    float* x2      = x1      + (long long)kB * kT * kD;    // B*T*256
    float* hff     = x2      + (long long)kB * kT * kD;    // B*T*2048

    const float scale = 0.17677669529663687f;  // 1/sqrt(32)
    dim3 blk(256);
    int tM77 = (kT + BM - 1) / BM;     // 3
    int tM400 = (kM1 + BM - 1) / BM;   // 13

    // 1. SA QKV: (B,77,768) = text @ sa_in_w^T + sa_in_b
    gemm_kernel<<<dim3(768 / BN, tM77, kB), blk, 0, stream>>>(
        text, (long long)kT * kD, kD,
        sa_in_w, (long long)3 * kD * kD, kD,
        sa_in_b, 3 * kD,
        qkv_sa, (long long)kT * 768, 768,
        sid, kT, 768, kD, 0);

    // 2. SA attention -> attnbuf (B,77,256)
    attn_kernel<<<dim3(kT, kH, kB), dim3(64), 0, stream>>>(
        qkv_sa,       (long long)kT * 768, 768,
        qkv_sa + 256, (long long)kT * 768, 768,
        qkv_sa + 512, (long long)kT * 768, 768,
        tmask, kT, tmask, kT, kT, kT,
        attnbuf, (long long)kT * kD, kD, scale);

    // 3. SA out-proj -> tmp
    gemm_kernel<<<dim3(kD / BN, tM77, kB), blk, 0, stream>>>(
        attnbuf, (long long)kT * kD, kD,
        sa_out_w, (long long)kD * kD, kD,
        sa_out_b, kD,
        tmp, (long long)kT * kD, kD,
        sid, kT, kD, kD, 0);

    // 4. x1 = LN1(tmp + text)
    addln_kernel<<<dim3(kT, kB), blk, 0, stream>>>(tmp, text, ln1_w, ln1_b, sid, x1);

    // 5. CA Q: x1 @ wq^T (rows 0..255 of ca_in_w)
    gemm_kernel<<<dim3(kD / BN, tM77, kB), blk, 0, stream>>>(
        x1, (long long)kT * kD, kD,
        ca_in_w, (long long)3 * kD * kD, kD,
        ca_in_b, 3 * kD,
        q_ca, (long long)kT * kD, kD,
        sid, kT, kD, kD, 0);

    // 6. CA KV: mem(=concat(im1,im2)) @ [wk;wv]^T -> kv_ca (B,800,512)
    gemm_kernel<<<dim3(512 / BN, tM400, kB), blk, 0, stream>>>(
        im1, (long long)kM1 * kD, kD,
        ca_in_w + (long long)kD * kD, (long long)3 * kD * kD, kD,
        ca_in_b + kD, 3 * kD,
        kv_ca, (long long)kMKV * 512, 512,
        sid, kM1, 512, kD, 0);
    gemm_kernel<<<dim3(512 / BN, tM400, kB), blk, 0, stream>>>(
        im2, (long long)kM1 * kD, kD,
        ca_in_w + (long long)kD * kD, (long long)3 * kD * kD, kD,
        ca_in_b + kD, 3 * kD,
        kv_ca + (long long)kM1 * 512, (long long)kMKV * 512, 512,
        sid, kM1, 512, kD, 0);

    // 7. CA attention -> attnbuf
    attn_kernel<<<dim3(kT, kH, kB), dim3(64), 0, stream>>>(
        q_ca,        (long long)kT * kD, kD,
        kv_ca,       (long long)kMKV * 512, 512,
        kv_ca + 256, (long long)kMKV * 512, 512,
        immk1, kM1, immk2, kM1, kM1, kMKV,
        attnbuf, (long long)kT * kD, kD, scale);

    // 8. CA out-proj -> tmp
    gemm_kernel<<<dim3(kD / BN, tM77, kB), blk, 0, stream>>>(
        attnbuf, (long long)kT * kD, kD,
        ca_out_w, (long long)kD * kD, kD,
        ca_out_b, kD,
        tmp, (long long)kT * kD, kD,
        sid, kT, kD, kD, 0);

    // 9. x2 = LN2(tmp + x1)
    addln_kernel<<<dim3(kT, kB), blk, 0, stream>>>(tmp, x1, ln2_w, ln2_b, sid, x2);

    // 10. FFN1: hff = relu(x2 @ lin1_w^T + lin1_b)  (B,77,2048)
    gemm_kernel<<<dim3(kDFF / BN, tM77, kB), blk, 0, stream>>>(
        x2, (long long)kT * kD, kD,
        lin1_w, (long long)kDFF * kD, kD,
        lin1_b, kDFF,
        hff, (long long)kT * kDFF, kDFF,
        sid, kT, kDFF, kD, 1);

    // 11. FFN2: tmp = hff @ lin2_w^T + lin2_b
    gemm_kernel<<<dim3(kD / BN, tM77, kB), blk, 0, stream>>>(
        hff, (long long)kT * kDFF, kDFF,
        lin2_w, (long long)kD * kDFF, kDFF,
        lin2_b, kD,
        tmp, (long long)kT * kD, kD,
        sid, kT, kD, kDFF, 0);

    // 12. out = LN3(tmp + x2)
    addln_kernel<<<dim3(kT, kB), blk, 0, stream>>>(tmp, x2, ln3_w, ln3_b, sid, out);
}

// Round 2
// 1110.822 us; speedup vs baseline: 2.6528x; 2.6528x over previous
//
#include <hip/hip_runtime.h>
#include <hip/hip_bf16.h>
#include <math.h>

constexpr int kB   = 64;
constexpr int kT   = 77;
constexpr int kD   = 256;
constexpr int kH   = 8;
constexpr int kDH  = 32;
constexpr int kDFF = 2048;
constexpr int kM1  = 400;
constexpr int kMKV = 800;
constexpr float kEPS = 1e-5f;
constexpr float kNEG = -1000000000.0f;

typedef __attribute__((ext_vector_type(8))) short short8;
typedef __attribute__((ext_vector_type(4))) float floatx4;

// RNE fp32 -> bf16 pair, packed into one uint (low = x, high = y)
__device__ __forceinline__ unsigned pkbf(float x, float y) {
    unsigned ux = __float_as_uint(x), uy = __float_as_uint(y);
    ux = (ux + 0x7fffu + ((ux >> 16) & 1u)) >> 16;
    uy = (uy + 0x7fffu + ((uy >> 16) & 1u)) & 0xffff0000u;
    return ux | uy;
}

// ---------------------------------------------------------------------------
// MFMA bf16 GEMM: C[b] = A[b] @ W[sid[b]]^T + bias[sid[b]]  (opt. ReLU)
// A rows < splitM from A1, >= splitM from A2 (for the CA-KV concat).
// Tile 128x128xBK64; 256 threads = 4 waves in 2x2, each wave does 64x64 via
// 4x4 mfma_f32_16x16x32_bf16. LDS tiles: [128][88] ushort (176B row stride:
// 16B-aligned for ds_read_b128, bank pattern 12m%32 -> 2-way only = free).
// Grid.x = tilesN*tilesM flattened y-fastest: consecutive blocks share W tile.
// ---------------------------------------------------------------------------
__global__ __launch_bounds__(256) void mfma_gemm(
    const float* __restrict__ A1, long long sA1,
    const float* __restrict__ A2, long long sA2, int splitM, int lda,
    const float* __restrict__ W, long long sW, int ldw,
    const float* __restrict__ bias, long long sB,
    float* __restrict__ C, long long sC, int ldc,
    const int* __restrict__ sid, int M, int N, int K, int tilesM, int relu)
{
    __shared__ unsigned short As[128][88];
    __shared__ unsigned short Bs[128][88];

    int b = blockIdx.z;
    int s = sid[b];
    int ty = blockIdx.x % tilesM;          // row tile (fastest -> W-tile reuse)
    int tx = blockIdx.x / tilesM;          // col tile
    int tm0 = ty * 128, tn0 = tx * 128;

    const float* Wb = W + (long long)s * sW;
    const float* Bb = bias + (long long)s * sB;
    float* Cb = C + (long long)b * sC;

    int t = threadIdx.x;
    int lane = t & 63, wv = t >> 6;
    int wm = wv >> 1, wn = wv & 1;
    int q = lane >> 4, mrow = lane & 15;

    floatx4 acc[4][4] = {};

    for (int k0 = 0; k0 < K; k0 += 64) {
        // Stage A (128x64 fp32 -> bf16). 16 lanes x float4 per row, coalesced.
        #pragma unroll
        for (int p = 0; p < 8; p++) {
            int row = (t >> 4) + 16 * p;
            int kf  = (t & 15) * 4;
            int ar = tm0 + row;
            float4 v = make_float4(0.f, 0.f, 0.f, 0.f);
            if (ar < M) {
                const float* src = (ar < splitM)
                    ? (A1 + (long long)b * sA1 + (long long)ar * lda)
                    : (A2 + (long long)b * sA2 + (long long)(ar - splitM) * lda);
                v = *(const float4*)(src + k0 + kf);
            }
            *(uint2*)&As[row][kf] = make_uint2(pkbf(v.x, v.y), pkbf(v.z, v.w));
        }
        // Stage B (W rows tn0..tn0+127; N is always a multiple of 128)
        #pragma unroll
        for (int p = 0; p < 8; p++) {
            int row = (t >> 4) + 16 * p;
            int kf  = (t & 15) * 4;
            const float* src = Wb + (long long)(tn0 + row) * ldw + k0 + kf;
            float4 v = *(const float4*)src;
            *(uint2*)&Bs[row][kf] = make_uint2(pkbf(v.x, v.y), pkbf(v.z, v.w));
        }
        __syncthreads();

        #pragma unroll
        for (int ks = 0; ks < 2; ks++) {
            int kk = ks * 32 + q * 8;   // A[m][k]: m=lane&15, k=quad*8+j
            short8 af[4], bfr[4];
            #pragma unroll
            for (int i = 0; i < 4; i++) {
                af[i]  = *(const short8*)&As[wm * 64 + i * 16 + mrow][kk];
                bfr[i] = *(const short8*)&Bs[wn * 64 + i * 16 + mrow][kk];
            }
            #pragma unroll
            for (int mi = 0; mi < 4; mi++)
                #pragma unroll
                for (int ni = 0; ni < 4; ni++)
                    acc[mi][ni] = __builtin_amdgcn_mfma_f32_16x16x32_bf16(
                        af[mi], bfr[ni], acc[mi][ni], 0, 0, 0);
        }
        __syncthreads();
    }

    // Epilogue: C/D layout col=lane&15, row=(lane>>4)*4+reg
    #pragma unroll
    for (int ni = 0; ni < 4; ni++) {
        int cgl = tn0 + wn * 64 + ni * 16 + mrow;
        float bv = Bb[cgl];
        #pragma unroll
        for (int mi = 0; mi < 4; mi++) {
            #pragma unroll
            for (int e = 0; e < 4; e++) {
                int r = tm0 + wm * 64 + mi * 16 + q * 4 + e;
                if (r < M) {
                    float o = acc[mi][ni][e] + bv;
                    if (relu) o = fmaxf(o, 0.f);
                    Cb[(long long)r * ldc + cgl] = o;
                }
            }
        }
    }
}

// ---------------------------------------------------------------------------
// Attention v2: block per (b, h, 32-q-row tile). 256 threads.
// K/V/mask staged in LDS (coalesced), Q rows in registers, online softmax.
// Phase A: thread (qg=t>>4 rows 2qg,2qg+1; jl=t&15) -> 2x4 scores per j-group.
// Stats: 32 threads, one per q-row.  Phase B: thread -> rows 2qg x d=2*jl..+1.
// ---------------------------------------------------------------------------
__global__ __launch_bounds__(256) void attn2(
    const float* __restrict__ Q, long long sQ, int ldq,
    const float* __restrict__ Kp, long long sK, int ldk,
    const float* __restrict__ Vp, long long sV, int ldv,
    const unsigned char* __restrict__ m1, int sM1,
    const unsigned char* __restrict__ m2, int sM2,
    int split, int nk, int ntiles,
    float* __restrict__ O, long long sO, int ldo, float scale)
{
    __shared__ float Ks[64][36];
    __shared__ float Vs[64][36];
    __shared__ float S[32][68];
    __shared__ float mk[64];
    __shared__ float mrowL[32], lrowL[32], alphaL[32];

    int t = threadIdx.x;
    int qt = blockIdx.x, h = blockIdx.y, b = blockIdx.z;
    int qbase = qt * 32;

    const float* Qb = Q + (long long)b * sQ + h * kDH;
    const float* Kb = Kp + (long long)b * sK + h * kDH;
    const float* Vb = Vp + (long long)b * sV + h * kDH;

    int qg = t >> 4, jl = t & 15;
    int r0 = 2 * qg, r1 = r0 + 1;
    int gq0 = qbase + r0, gq1 = qbase + r1;

    float4 qa0[8], qa1[8];
    #pragma unroll
    for (int i = 0; i < 8; i++) {
        qa0[i] = (gq0 < kT) ? *(const float4*)(Qb + (long long)gq0 * ldq + i * 4)
                            : make_float4(0.f, 0.f, 0.f, 0.f);
        qa1[i] = (gq1 < kT) ? *(const float4*)(Qb + (long long)gq1 * ldq + i * 4)
                            : make_float4(0.f, 0.f, 0.f, 0.f);
    }
    float oa00 = 0.f, oa01 = 0.f, oa10 = 0.f, oa11 = 0.f;
    if (t < 32) { mrowL[t] = -INFINITY; lrowL[t] = 0.f; }

    for (int tile = 0; tile < ntiles; tile++) {
        int jt0 = tile * 64;
        __syncthreads();   // previous phase B done before restaging

        // Stage K/V tile (64x32 each), coalesced float4
        #pragma unroll
        for (int p = 0; p < 2; p++) {
            int id = t + 256 * p;
            int j = id >> 3, dq = (id & 7) * 4;
            int gj = jt0 + j;
            float4 kv = (gj < nk) ? *(const float4*)(Kb + (long long)gj * ldk + dq)
                                  : make_float4(0.f, 0.f, 0.f, 0.f);
            float4 vv = (gj < nk) ? *(const float4*)(Vb + (long long)gj * ldv + dq)
                                  : make_float4(0.f, 0.f, 0.f, 0.f);
            *(float4*)&Ks[j][dq] = kv;
            *(float4*)&Vs[j][dq] = vv;
        }
        if (t < 64) {
            int gj = jt0 + t;
            float m = 0.f;
            if (gj < nk)
                m = ((gj < split) ? m1[b * sM1 + gj] : m2[b * sM2 + (gj - split)]) ? 1.f : 0.f;
            mk[t] = m;
        }
        __syncthreads();

        // Phase A: scores
        #pragma unroll
        for (int jj = 0; jj < 4; jj++) {
            int j = jl + 16 * jj;
            float a0 = 0.f, a1 = 0.f;
            #pragma unroll
            for (int d4 = 0; d4 < 8; d4++) {
                float4 kv = *(const float4*)&Ks[j][d4 * 4];
                a0 += qa0[d4].x * kv.x + qa0[d4].y * kv.y + qa0[d4].z * kv.z + qa0[d4].w * kv.w;
                a1 += qa1[d4].x * kv.x + qa1[d4].y * kv.y + qa1[d4].z * kv.z + qa1[d4].w * kv.w;
            }
            int gj = jt0 + j;
            float s0, s1;
            if (gj < nk) {
                float msk = mk[j];
                s0 = (msk != 0.f) ? kNEG : a0 * scale;
                s1 = (msk != 0.f) ? kNEG : a1 * scale;
            } else {
                s0 = -INFINITY; s1 = -INFINITY;
            }
            S[r0][j] = s0;
            S[r1][j] = s1;
        }
        __syncthreads();

        // Stats: online softmax update, one thread per q-row
        if (t < 32) {
            float mo = mrowL[t], lo = lrowL[t];
            float mt = -INFINITY;
            #pragma unroll
            for (int i = 0; i < 16; i++) {
                float4 sv = *(const float4*)&S[t][i * 4];
                mt = fmaxf(mt, fmaxf(fmaxf(sv.x, sv.y), fmaxf(sv.z, sv.w)));
            }
            float mn = fmaxf(mo, mt);
            float al = __expf(mo - mn);   // exp(-inf)=0 on first tile
            float ln = lo * al;
            #pragma unroll
            for (int i = 0; i < 16; i++) {
                float4 sv = *(const float4*)&S[t][i * 4];
                sv.x = __expf(sv.x - mn); sv.y = __expf(sv.y - mn);
                sv.z = __expf(sv.z - mn); sv.w = __expf(sv.w - mn);
                ln += sv.x + sv.y + sv.z + sv.w;
                *(float4*)&S[t][i * 4] = sv;
            }
            mrowL[t] = mn; lrowL[t] = ln; alphaL[t] = al;
        }
        __syncthreads();

        // Phase B: O += P @ V with rescale
        float al0 = alphaL[r0], al1 = alphaL[r1];
        oa00 *= al0; oa01 *= al0; oa10 *= al1; oa11 *= al1;
        #pragma unroll
        for (int j4 = 0; j4 < 64; j4 += 4) {
            float4 p0 = *(const float4*)&S[r0][j4];
            float4 p1 = *(const float4*)&S[r1][j4];
            const float* p0a = (const float*)&p0;
            const float* p1a = (const float*)&p1;
            #pragma unroll
            for (int e = 0; e < 4; e++) {
                float2 v = *(const float2*)&Vs[j4 + e][2 * jl];
                oa00 += p0a[e] * v.x; oa01 += p0a[e] * v.y;
                oa10 += p1a[e] * v.x; oa11 += p1a[e] * v.y;
            }
        }
    }

    float li0 = 1.f / lrowL[r0];
    float li1 = 1.f / lrowL[r1];
    if (gq0 < kT) {
        float2 o = make_float2(oa00 * li0, oa01 * li0);
        *(float2*)(O + (long long)b * sO + (long long)gq0 * ldo + h * kDH + 2 * jl) = o;
    }
    if (gq1 < kT) {
        float2 o = make_float2(oa10 * li1, oa11 * li1);
        *(float2*)(O + (long long)b * sO + (long long)gq1 * ldo + h * kDH + 2 * jl) = o;
    }
}

// ---------------------------------------------------------------------------
// Fused residual-add + LayerNorm over D=256. Block = 256 threads = one row.
// ---------------------------------------------------------------------------
__global__ __launch_bounds__(256) void addln_kernel(
    const float* __restrict__ A, const float* __restrict__ R,
    const float* __restrict__ w, const float* __restrict__ bb,
    const int* __restrict__ sid, float* __restrict__ O)
{
    int t = blockIdx.x, b = blockIdx.y, d = threadIdx.x;
    long long base = ((long long)(b * kT + t)) * kD;
    float x = A[base + d] + R[base + d];

    __shared__ float r1[4], r2[4];
    int wid = d >> 6;

    float sacc = x;
    #pragma unroll
    for (int off = 32; off >= 1; off >>= 1) sacc += __shfl_xor(sacc, off);
    if ((d & 63) == 0) r1[wid] = sacc;
    __syncthreads();
    float mean = (r1[0] + r1[1] + r1[2] + r1[3]) * (1.0f / 256.0f);

    float diff = x - mean;
    float s2 = diff * diff;
    #pragma unroll
    for (int off = 32; off >= 1; off >>= 1) s2 += __shfl_xor(s2, off);
    if ((d & 63) == 0) r2[wid] = s2;
    __syncthreads();
    float var = (r2[0] + r2[1] + r2[2] + r2[3]) * (1.0f / 256.0f);

    int s = sid[b];
    float y = diff * rsqrtf(var + kEPS) * w[s * kD + d] + bb[s * kD + d];
    O[base + d] = y;
}

// ---------------------------------------------------------------------------
// Launch
// ---------------------------------------------------------------------------
extern "C" void kernel_launch(void* const* d_in, const int* in_sizes, int n_in,
                              void* d_out, int out_size, void* d_ws, size_t ws_size,
                              hipStream_t stream)
{
    const float*         text   = (const float*)d_in[0];
    const unsigned char* tmask  = (const unsigned char*)d_in[1];
    const float*         im1    = (const float*)d_in[2];
    const unsigned char* immk1  = (const unsigned char*)d_in[3];
    const float*         im2    = (const float*)d_in[4];
    const unsigned char* immk2  = (const unsigned char*)d_in[5];
    const int*           sid    = (const int*)d_in[6];
    const float* sa_in_w  = (const float*)d_in[7];
    const float* sa_in_b  = (const float*)d_in[8];
    const float* sa_out_w = (const float*)d_in[9];
    const float* sa_out_b = (const float*)d_in[10];
    const float* ca_in_w  = (const float*)d_in[11];
    const float* ca_in_b  = (const float*)d_in[12];
    const float* ca_out_w = (const float*)d_in[13];
    const float* ca_out_b = (const float*)d_in[14];
    const float* lin1_w   = (const float*)d_in[15];
    const float* lin1_b   = (const float*)d_in[16];
    const float* lin2_w   = (const float*)d_in[17];
    const float* lin2_b   = (const float*)d_in[18];
    const float* ln1_w    = (const float*)d_in[19];
    const float* ln1_b    = (const float*)d_in[20];
    const float* ln2_w    = (const float*)d_in[21];
    const float* ln2_b    = (const float*)d_in[22];
    const float* ln3_w    = (const float*)d_in[23];
    const float* ln3_b    = (const float*)d_in[24];
    float* out = (float*)d_out;

    // Workspace layout (floats)
    float* ws = (float*)d_ws;
    float* qkv_sa  = ws;                                   // B*T*768
    float* q_ca    = qkv_sa  + (long long)kB * kT * 768;   // B*T*256
    float* kv_ca   = q_ca    + (long long)kB * kT * kD;    // B*800*512
    float* attnbuf = kv_ca   + (long long)kB * kMKV * 512; // B*T*256
    float* tmp     = attnbuf + (long long)kB * kT * kD;    // B*T*256
    float* x1      = tmp     + (long long)kB * kT * kD;    // B*T*256
    float* x2      = x1      + (long long)kB * kT * kD;    // B*T*256
    float* hff     = x2      + (long long)kB * kT * kD;    // B*T*2048

    const float scale = 0.17677669529663687f;  // 1/sqrt(32)
    dim3 blk(256);

    auto gemm = [&](const float* A1, long long sA1, const float* A2, long long sA2,
                    int splitM, int lda,
                    const float* W, long long sW, int ldw,
                    const float* bias, long long sB,
                    float* C, long long sC, int ldc,
                    int M, int N, int K, int relu) {
        int tm = (M + 127) / 128, tn = N / 128;
        mfma_gemm<<<dim3(tm * tn, 1, kB), blk, 0, stream>>>(
            A1, sA1, A2, sA2, splitM, lda, W, sW, ldw, bias, sB,
            C, sC, ldc, sid, M, N, K, tm, relu);
    };

    // 1. SA QKV: (B,77,768)
    gemm(text, (long long)kT * kD, text, 0, kT, kD,
         sa_in_w, (long long)3 * kD * kD, kD, sa_in_b, 3 * kD,
         qkv_sa, (long long)kT * 768, 768, kT, 768, kD, 0);

    // 2. SA attention -> attnbuf
    attn2<<<dim3(3, kH, kB), blk, 0, stream>>>(
        qkv_sa,       (long long)kT * 768, 768,
        qkv_sa + 256, (long long)kT * 768, 768,
        qkv_sa + 512, (long long)kT * 768, 768,
        tmask, kT, tmask, kT, kT, kT, 2,
        attnbuf, (long long)kT * kD, kD, scale);

    // 3. SA out-proj -> tmp
    gemm(attnbuf, (long long)kT * kD, attnbuf, 0, kT, kD,
         sa_out_w, (long long)kD * kD, kD, sa_out_b, kD,
         tmp, (long long)kT * kD, kD, kT, kD, kD, 0);

    // 4. x1 = LN1(tmp + text)
    addln_kernel<<<dim3(kT, kB), blk, 0, stream>>>(tmp, text, ln1_w, ln1_b, sid, x1);

    // 5. CA Q (rows 0..255 of ca_in_w)
    gemm(x1, (long long)kT * kD, x1, 0, kT, kD,
         ca_in_w, (long long)3 * kD * kD, kD, ca_in_b, 3 * kD,
         q_ca, (long long)kT * kD, kD, kT, kD, kD, 0);

    // 6. CA KV: concat(im1,im2) @ [wk;wv]^T -> kv_ca (B,800,512), single launch
    gemm(im1, (long long)kM1 * kD, im2, (long long)kM1 * kD, kM1, kD,
         ca_in_w + (long long)kD * kD, (long long)3 * kD * kD, kD,
         ca_in_b + kD, 3 * kD,
         kv_ca, (long long)kMKV * 512, 512, kMKV, 512, kD, 0);

    // 7. CA attention -> attnbuf
    attn2<<<dim3(3, kH, kB), blk, 0, stream>>>(
        q_ca,        (long long)kT * kD, kD,
        kv_ca,       (long long)kMKV * 512, 512,
        kv_ca + 256, (long long)kMKV * 512, 512,
        immk1, kM1, immk2, kM1, kM1, kMKV, 13,
        attnbuf, (long long)kT * kD, kD, scale);

    // 8. CA out-proj -> tmp
    gemm(attnbuf, (long long)kT * kD, attnbuf, 0, kT, kD,
         ca_out_w, (long long)kD * kD, kD, ca_out_b, kD,
         tmp, (long long)kT * kD, kD, kT, kD, kD, 0);

    // 9. x2 = LN2(tmp + x1)
    addln_kernel<<<dim3(kT, kB), blk, 0, stream>>>(tmp, x1, ln2_w, ln2_b, sid, x2);

    // 10. FFN1: hff = relu(x2 @ lin1_w^T + lin1_b)
    gemm(x2, (long long)kT * kD, x2, 0, kT, kD,
         lin1_w, (long long)kDFF * kD, kD, lin1_b, kDFF,
         hff, (long long)kT * kDFF, kDFF, kT, kDFF, kD, 1);

    // 11. FFN2: tmp = hff @ lin2_w^T + lin2_b
    gemm(hff, (long long)kT * kDFF, hff, 0, kT, kDFF,
         lin2_w, (long long)kD * kDFF, kDFF, lin2_b, kD,
         tmp, (long long)kT * kD, kD, kT, kD, kDFF, 0);

    // 12. out = LN3(tmp + x2)
    addln_kernel<<<dim3(kT, kB), blk, 0, stream>>>(tmp, x2, ln3_w, ln3_b, sid, out);
}